// Round 3
// baseline (1008.630 us; speedup 1.0000x reference)
//
#include <hip/hip_runtime.h>
#include <hip/hip_bf16.h>
#include <cstdint>
#include <cstddef>

typedef unsigned short u16;
typedef __attribute__((ext_vector_type(8))) short bf16x8;   // MFMA A/B frag (8 bf16)
typedef __attribute__((ext_vector_type(4))) float f32x4;    // MFMA C/D frag
typedef __attribute__((ext_vector_type(4))) unsigned short u16x4;

#define B_ 4
#define N_ 8192
#define D_ 64
#define H_ 128
#define E_ 256
#define C_ 16

// ---------- helpers ----------
__device__ __forceinline__ u16 f2bf(float f) {
  unsigned u = __builtin_bit_cast(unsigned, f);
  u += 0x7fffu + ((u >> 16) & 1u);          // RNE
  return (u16)(u >> 16);
}
__device__ __forceinline__ float bf2f(u16 u) {
  return __builtin_bit_cast(float, ((unsigned)u) << 16);
}
__device__ __forceinline__ float bflo(unsigned u) {
  return __builtin_bit_cast(float, u << 16);
}
__device__ __forceinline__ float bfhi(unsigned u) {
  return __builtin_bit_cast(float, u & 0xffff0000u);
}

__device__ __forceinline__ float wave_sum(float v) {
  v += __shfl_xor(v, 32, 64); v += __shfl_xor(v, 16, 64); v += __shfl_xor(v, 8, 64);
  v += __shfl_xor(v, 4, 64);  v += __shfl_xor(v, 2, 64);  v += __shfl_xor(v, 1, 64);
  return v;
}
__device__ __forceinline__ float wave_max(float v) {
  v = fmaxf(v, __shfl_xor(v, 32, 64)); v = fmaxf(v, __shfl_xor(v, 16, 64));
  v = fmaxf(v, __shfl_xor(v, 8, 64));  v = fmaxf(v, __shfl_xor(v, 4, 64));
  v = fmaxf(v, __shfl_xor(v, 2, 64));  v = fmaxf(v, __shfl_xor(v, 1, 64));
  return v;
}

__device__ __forceinline__ void gld16(const void* g, void* l) {
  __builtin_amdgcn_global_load_lds((const __attribute__((address_space(1))) void*)g,
                                   (__attribute__((address_space(3))) void*)l, 16, 0, 0);
}

// ---------- zero init (for atomic rowsum) ----------
__global__ __launch_bounds__(256) void k_zero(float* __restrict__ p, int n) {
  int i = blockIdx.x * 256 + threadIdx.x;
  if (i < n) p[i] = 0.f;
}

// ---------- transpose + fused rowsum: adjT[i][j]=bf16(adj[j][i]); rsum[j]+=partial ----------
__global__ __launch_bounds__(256) void k_transpose(const float* __restrict__ adj, u16* __restrict__ adjT,
                                                   float* __restrict__ rsum) {
  __shared__ float tile[64][65];
  int bi = blockIdx.x & 127, bj = blockIdx.x >> 7;
  int i0 = bi * 64, j0 = bj * 64;
  int t = threadIdx.x;
#pragma unroll
  for (int q = 0; q < 4; ++q) {
    int idx = q * 256 + t; int jl = idx >> 4, c4 = idx & 15;
    float4 v = *(const float4*)(adj + (size_t)(j0 + jl) * N_ + i0 + c4 * 4);
    tile[jl][c4 * 4 + 0] = v.x; tile[jl][c4 * 4 + 1] = v.y;
    tile[jl][c4 * 4 + 2] = v.z; tile[jl][c4 * 4 + 3] = v.w;
    float s = (v.x + v.y) + (v.z + v.w);
    s += __shfl_xor(s, 1, 64); s += __shfl_xor(s, 2, 64);
    s += __shfl_xor(s, 4, 64); s += __shfl_xor(s, 8, 64);
    if ((t & 15) == 0) atomicAdd(&rsum[j0 + jl], s);
  }
  __syncthreads();
#pragma unroll
  for (int q = 0; q < 4; ++q) {
    int idx = q * 256 + t; int il = idx >> 4, c4 = idx & 15;
    u16x4 o;
    o.x = f2bf(tile[c4 * 4 + 0][il]); o.y = f2bf(tile[c4 * 4 + 1][il]);
    o.z = f2bf(tile[c4 * 4 + 2][il]); o.w = f2bf(tile[c4 * 4 + 3][il]);
    *(u16x4*)(adjT + (size_t)(i0 + il) * N_ + j0 + c4 * 4) = o;
  }
}

// ---------- rsum -> rr = rsum^-0.5 ----------
__global__ __launch_bounds__(256) void k_rsqrt(const float* __restrict__ rsum, float* __restrict__ rr) {
  int i = blockIdx.x * 256 + threadIdx.x;
  float s = rsum[i];
  rr[i] = s > 0.f ? rsqrtf(s) : 0.f;
}

// ---------- xt[b*64+d][j] = bf16(x[b][j][d] * r[j]) ----------
__global__ __launch_bounds__(256) void k_xt(const float* __restrict__ x, const float* __restrict__ rr,
                                            u16* __restrict__ xt) {
  __shared__ float tile[64][65];
  int b = blockIdx.x >> 7, j0 = (blockIdx.x & 127) * 64;
  int t = threadIdx.x;
#pragma unroll
  for (int q = 0; q < 4; ++q) {
    int idx = q * 256 + t; int jl = idx >> 4, c4 = idx & 15;
    float4 v = *(const float4*)(x + ((size_t)b * N_ + j0 + jl) * D_ + c4 * 4);
    float rv = rr[j0 + jl];
    tile[jl][c4 * 4 + 0] = v.x * rv; tile[jl][c4 * 4 + 1] = v.y * rv;
    tile[jl][c4 * 4 + 2] = v.z * rv; tile[jl][c4 * 4 + 3] = v.w * rv;
  }
  __syncthreads();
#pragma unroll
  for (int q = 0; q < 4; ++q) {
    int idx = q * 256 + t; int dl = idx >> 4, c4 = idx & 15;
    u16x4 o;
    o.x = f2bf(tile[c4 * 4 + 0][dl]); o.y = f2bf(tile[c4 * 4 + 1][dl]);
    o.z = f2bf(tile[c4 * 4 + 2][dl]); o.w = f2bf(tile[c4 * 4 + 3][dl]);
    *(u16x4*)(xt + (size_t)(b * 64 + dl) * N_ + j0 + c4 * 4) = o;
  }
}

// ---------- swapped split-K GEMM: Cp[ks][c][i] = bf16( sum_k A[c][k]*B[i][k] ) ----------
// A: [M][N_] small (xt / g1t), B: adjT [N_][N_] read EXACTLY ONCE, BM=64, BN=256.
// bm fastest in blockIdx so m-blocks sharing a B tile are dispatch-adjacent (L2 hits).
template<int KS>
__global__ __launch_bounds__(256) void k_gemmT(const u16* __restrict__ A, const u16* __restrict__ B,
                                               u16* __restrict__ Cp, int M) {
  constexpr int BK = 32, BM = 64, BN = 256;
  __shared__ __align__(16) u16 As[BM * BK];   // 4 KB
  __shared__ __align__(16) u16 Bs[BN * BK];   // 16 KB
  const int tid = threadIdx.x;
  const int nmb = M >> 6;
  const int bm = blockIdx.x % nmb;
  const int rest = blockIdx.x / nmb;
  const int kb = rest % KS;
  const int bn = rest / KS;
  const int m0 = bm * BM, n0 = bn * BN;
  const int kbeg = kb * (N_ / KS), kend = kbeg + N_ / KS;
  const int wave = tid >> 6, lane = tid & 63;
  const int wm = (wave >> 1) * 32, wn = (wave & 1) * 128;
  const int lr = lane & 15, lk = lane >> 4;

  f32x4 acc[2][8];
#pragma unroll
  for (int a = 0; a < 2; ++a)
#pragma unroll
    for (int b = 0; b < 8; ++b) acc[a][b] = (f32x4){0.f, 0.f, 0.f, 0.f};

  const u16* Ab = A + (size_t)(m0 + (tid >> 2)) * N_ + (tid & 3) * 8;
  const u16* Bb = B + (size_t)(n0 + (tid >> 2)) * N_ + (tid & 3) * 8;
  u16* As_dst = As + (tid & 192) * 8;

  for (int k0 = kbeg; k0 < kend; k0 += BK) {
    gld16(Ab + k0, As_dst);
#pragma unroll
    for (int it = 0; it < 4; ++it)
      gld16(Bb + (size_t)it * 64 * N_ + k0, Bs + (it * 256 + (tid & 192)) * 8);
    __syncthreads();
    bf16x8 av[2], bv[8];
    av[0] = *(const bf16x8*)(As + (wm + lr) * BK + lk * 8);
    av[1] = *(const bf16x8*)(As + (wm + 16 + lr) * BK + lk * 8);
#pragma unroll
    for (int f = 0; f < 8; ++f)
      bv[f] = *(const bf16x8*)(Bs + (wn + f * 16 + lr) * BK + lk * 8);
#pragma unroll
    for (int fm = 0; fm < 2; ++fm)
#pragma unroll
      for (int fn = 0; fn < 8; ++fn)
        acc[fm][fn] = __builtin_amdgcn_mfma_f32_16x16x32_bf16(av[fm], bv[fn], acc[fm][fn], 0, 0, 0);
    __syncthreads();
  }
  u16* Cs = Cp + (size_t)kb * M * N_;
#pragma unroll
  for (int fm = 0; fm < 2; ++fm) {
    int row0 = m0 + wm + fm * 16 + lk * 4;
#pragma unroll
    for (int fn = 0; fn < 8; ++fn) {
      int col = n0 + wn + fn * 16 + lr;
#pragma unroll
      for (int p = 0; p < 4; ++p)
        Cs[(size_t)(row0 + p) * N_ + col] = f2bf(acc[fm][fn][p]);
    }
  }
}

// ---------- epi1: 16 nodes/block. y=r*sum(T1p)+x ; z=y@W1+b1 ; L2norm ; relu ; BN ; g1n,g1t ----------
// T1p layout: [ks][c][i] (i-contiguous), KS1=4
__global__ __launch_bounds__(256) void k_epi1(const u16* __restrict__ T1p, const float* __restrict__ x,
    const float* __restrict__ rr, const float* __restrict__ W1, const float* __restrict__ b1,
    float* __restrict__ g1n, u16* __restrict__ g1t) {
  union SharedU { float ys[16][256]; u16 gb[512][18]; };
  __shared__ SharedU su;                 // 18 KB
  __shared__ float zbuf[16][512];        // 32 KB
  __shared__ float rs[16];
  const int t = threadIdx.x;
  const int i0 = blockIdx.x * 16;
  constexpr size_t SL = (size_t)256 * N_;
  if (t < 16) rs[t] = rr[i0 + t];
  __syncthreads();
  // phase 0: per thread c=t, 16 nodes, sum KS=4 slices
  {
    float accv[16];
#pragma unroll
    for (int n = 0; n < 16; ++n) accv[n] = 0.f;
    const u16* tp = T1p + (size_t)t * N_ + i0;
#pragma unroll
    for (int ks = 0; ks < 4; ++ks) {
      const uint4* p = (const uint4*)(tp + ks * SL);
      uint4 a = p[0], b = p[1];
      accv[0]  += bflo(a.x); accv[1]  += bfhi(a.x); accv[2]  += bflo(a.y); accv[3]  += bfhi(a.y);
      accv[4]  += bflo(a.z); accv[5]  += bfhi(a.z); accv[6]  += bflo(a.w); accv[7]  += bfhi(a.w);
      accv[8]  += bflo(b.x); accv[9]  += bfhi(b.x); accv[10] += bflo(b.y); accv[11] += bfhi(b.y);
      accv[12] += bflo(b.z); accv[13] += bfhi(b.z); accv[14] += bflo(b.w); accv[15] += bfhi(b.w);
    }
    int bb = t >> 6, d = t & 63;
#pragma unroll
    for (int n = 0; n < 16; ++n)
      su.ys[n][t] = rs[n] * accv[n] + x[((size_t)bb * N_ + i0 + n) * D_ + d];
  }
  // phase 1: W1 column into registers
  const int h = t & 127, bh = t >> 7;
  float w[64];
#pragma unroll
  for (int d = 0; d < 64; ++d) w[d] = W1[d * H_ + h];
  float b1h = b1[h];
  __syncthreads();
  // phase 2: z[n][c'] for c' = b*128+h
  for (int n = 0; n < 16; ++n) {
    float za = b1h, zb = b1h;
#pragma unroll
    for (int d = 0; d < 64; ++d) {
      za += su.ys[n][bh * 64 + d] * w[d];
      zb += su.ys[n][(bh + 2) * 64 + d] * w[d];
    }
    zbuf[n][bh * 128 + h] = za;
    zbuf[n][(bh + 2) * 128 + h] = zb;
  }
  __syncthreads();
  // phase 3: per-wave nodes, no barriers
  const int wv = t >> 6, lane = t & 63;
#pragma unroll
  for (int nn = 0; nn < 4; ++nn) {
    int n = wv * 4 + nn;
    float v[8], nb2[8];
#pragma unroll
    for (int q = 0; q < 8; ++q) { v[q] = zbuf[n][q * 64 + lane]; }
#pragma unroll
    for (int q = 0; q < 8; ++q) nb2[q] = wave_sum(v[q] * v[q]);
    float inv0 = 1.f / fmaxf(sqrtf(nb2[0] + nb2[1]), 1e-12f);
    float inv1 = 1.f / fmaxf(sqrtf(nb2[2] + nb2[3]), 1e-12f);
    float inv2 = 1.f / fmaxf(sqrtf(nb2[4] + nb2[5]), 1e-12f);
    float inv3 = 1.f / fmaxf(sqrtf(nb2[6] + nb2[7]), 1e-12f);
    float sc[4] = {inv0, inv1, inv2, inv3};
    float t1 = 0.f, t2 = 0.f;
#pragma unroll
    for (int q = 0; q < 8; ++q) {
      v[q] = fmaxf(v[q] * sc[q >> 1], 0.f);
      t1 += v[q]; t2 += v[q] * v[q];
    }
    float s1 = wave_sum(t1), s2 = wave_sum(t2);
    float m = s1 * (1.f / 512.f);
    float var = s2 * (1.f / 512.f) - m * m;
    float iv = rsqrtf(var + 1e-5f);
    float rv = rs[n];
#pragma unroll
    for (int q = 0; q < 8; ++q) {
      float g = (v[q] - m) * iv;
      g1n[(size_t)(i0 + n) * 512 + q * 64 + lane] = g;
      su.gb[q * 64 + lane][n] = f2bf(g * rv);
    }
  }
  __syncthreads();
  // phase 4: coalesced transposed write of g1t [c][j]
#pragma unroll
  for (int rep = 0; rep < 2; ++rep) {
    int c = rep * 256 + t;
    const unsigned* src = (const unsigned*)&su.gb[c][0];
    uint4 o0, o1;
    o0.x = src[0]; o0.y = src[1]; o0.z = src[2]; o0.w = src[3];
    o1.x = src[4]; o1.y = src[5]; o1.z = src[6]; o1.w = src[7];
    uint4* dst = (uint4*)(g1t + (size_t)c * N_ + i0);
    dst[0] = o0; dst[1] = o1;
  }
}

// ---------- epi2: y=r*sum(T2p)+g1 ; z=y@W2+b2 ; L2norm(e) ; relu ; BN ; g2n ----------
// T2p layout: [ks][c][i] (i-contiguous), KS2=2
__global__ __launch_bounds__(256) void k_epi2(const u16* __restrict__ T2p, const float* __restrict__ g1n,
    const float* __restrict__ rr, const float* __restrict__ W2, const float* __restrict__ b2,
    float* __restrict__ g2n) {
  __shared__ __align__(16) float ysm[8 * 512];     // 16 KB
  __shared__ __align__(16) float W2s[32 * 256];    // 32 KB
  __shared__ float red1[128];
  __shared__ float nv[32];
  __shared__ float redA[32], redB[32];
  __shared__ float mn[8], iv[8];
  __shared__ float rs2[8];
  constexpr size_t SL = (size_t)512 * N_;
  int i0 = blockIdx.x * 8, t = threadIdx.x;
  if (t < 8) rs2[t] = rr[i0 + t];
  __syncthreads();
#pragma unroll
  for (int half = 0; half < 2; ++half) {
    int c = half * 256 + t;
    const u16* p = T2p + (size_t)c * N_ + i0;
    uint4 a0 = *(const uint4*)p;
    uint4 a1 = *(const uint4*)(p + SL);
    float s[8];
    s[0] = bflo(a0.x) + bflo(a1.x); s[1] = bfhi(a0.x) + bfhi(a1.x);
    s[2] = bflo(a0.y) + bflo(a1.y); s[3] = bfhi(a0.y) + bfhi(a1.y);
    s[4] = bflo(a0.z) + bflo(a1.z); s[5] = bfhi(a0.z) + bfhi(a1.z);
    s[6] = bflo(a0.w) + bflo(a1.w); s[7] = bfhi(a0.w) + bfhi(a1.w);
#pragma unroll
    for (int n = 0; n < 8; ++n)
      ysm[n * 512 + c] = rs2[n] * s[n] + g1n[(size_t)(i0 + n) * 512 + c];
  }
  int e = t;
  float z[8][4];
#pragma unroll
  for (int n = 0; n < 8; ++n)
#pragma unroll
    for (int b = 0; b < 4; ++b) z[n][b] = 0.f;

  for (int hc = 0; hc < H_; hc += 32) {
    __syncthreads();
#pragma unroll
    for (int q = 0; q < 8; ++q) {
      int idx = q * 256 + t;
      ((float4*)W2s)[idx] = ((const float4*)(W2 + (size_t)hc * 256))[idx];
    }
    __syncthreads();
#pragma unroll
    for (int h4 = 0; h4 < 32; h4 += 4) {
      float w0 = W2s[(h4 + 0) * 256 + e];
      float w1 = W2s[(h4 + 1) * 256 + e];
      float w2 = W2s[(h4 + 2) * 256 + e];
      float w3 = W2s[(h4 + 3) * 256 + e];
#pragma unroll
      for (int n = 0; n < 8; ++n) {
#pragma unroll
        for (int b = 0; b < 4; ++b) {
          float4 y = *(const float4*)&ysm[n * 512 + b * 128 + hc + h4];
          z[n][b] += y.x * w0 + y.y * w1 + y.z * w2 + y.w * w3;
        }
      }
    }
  }
  float b2e = b2[e];
  int wave = t >> 6, lane = t & 63;
#pragma unroll
  for (int n = 0; n < 8; ++n)
#pragma unroll
    for (int b = 0; b < 4; ++b) {
      z[n][b] += b2e;
      float s = wave_sum(z[n][b] * z[n][b]);
      if (lane == 0) red1[n * 16 + b * 4 + wave] = s;
    }
  __syncthreads();
  if (t < 32) {
    float s = red1[t * 4 + 0] + red1[t * 4 + 1] + red1[t * 4 + 2] + red1[t * 4 + 3];
    nv[t] = fmaxf(sqrtf(s), 1e-12f);
  }
  __syncthreads();
#pragma unroll
  for (int n = 0; n < 8; ++n) {
    float s1 = 0.f, s2 = 0.f;
#pragma unroll
    for (int b = 0; b < 4; ++b) {
      z[n][b] = fmaxf(z[n][b] / nv[n * 4 + b], 0.f);
      s1 += z[n][b]; s2 += z[n][b] * z[n][b];
    }
    s1 = wave_sum(s1); s2 = wave_sum(s2);
    if (lane == 0) { redA[n * 4 + wave] = s1; redB[n * 4 + wave] = s2; }
  }
  __syncthreads();
  if (t < 8) {
    float s1 = redA[t * 4] + redA[t * 4 + 1] + redA[t * 4 + 2] + redA[t * 4 + 3];
    float s2 = redB[t * 4] + redB[t * 4 + 1] + redB[t * 4 + 2] + redB[t * 4 + 3];
    float m = s1 * (1.f / 1024.f), v = s2 * (1.f / 1024.f) - m * m;
    mn[t] = m; iv[t] = 1.f / sqrtf(v + 1e-5f);
  }
  __syncthreads();
#pragma unroll
  for (int n = 0; n < 8; ++n)
#pragma unroll
    for (int b = 0; b < 4; ++b)
      g2n[(size_t)(i0 + n) * 1024 + b * 256 + e] = (z[n][b] - mn[n]) * iv[n];
}

// ---------- pred ----------
__global__ __launch_bounds__(256) void k_pred(const float* __restrict__ g2n, const float* __restrict__ Wp,
    const float* __restrict__ bp, float* __restrict__ pred) {
  __shared__ __align__(16) float gs[8 * 1028];
  __shared__ __align__(16) float Wps[E_ * C_];
  int i0 = blockIdx.x * 8, t = threadIdx.x;
#pragma unroll
  for (int q = 0; q < 4; ++q) ((float4*)Wps)[q * 256 + t] = ((const float4*)Wp)[q * 256 + t];
#pragma unroll
  for (int q = 0; q < 8; ++q) {
    int idx = q * 256 + t; int n = idx >> 8, c4 = idx & 255;
    *(float4*)&gs[n * 1028 + c4 * 4] = *(const float4*)(g2n + (size_t)(i0 + n) * 1024 + c4 * 4);
  }
  __syncthreads();
#pragma unroll
  for (int s = 0; s < 2; ++s) {
    int o = s * 256 + t; int n = o >> 6, b = (o >> 4) & 3, c = o & 15;
    float acc = bp[c];
    const float* g = &gs[n * 1028 + b * 256];
#pragma unroll 16
    for (int e2 = 0; e2 < 256; e2 += 4) {
      float4 gv = *(const float4*)&g[e2];
      acc += gv.x * Wps[(e2 + 0) * 16 + c] + gv.y * Wps[(e2 + 1) * 16 + c]
           + gv.z * Wps[(e2 + 2) * 16 + c] + gv.w * Wps[(e2 + 3) * 16 + c];
    }
    pred[((size_t)b * N_ + i0 + n) * C_ + c] = acc;
  }
}

// ---------- softmax over node axis ----------
__global__ __launch_bounds__(256) void k_softmax(const float* __restrict__ pred, float* __restrict__ out) {
  int b = blockIdx.x >> 4, c = blockIdx.x & 15, t = threadIdx.x;
  const float* p = pred + (size_t)b * N_ * C_ + c;
  float* po = out + (size_t)b * N_ * C_ + c;
  float v[32];
  float mx = -3.4e38f;
#pragma unroll
  for (int k = 0; k < 32; ++k) { v[k] = p[(size_t)(t + 256 * k) * C_]; mx = fmaxf(mx, v[k]); }
  mx = wave_max(mx);
  __shared__ float pm[4];
  __shared__ float ps[4];
  int wave = t >> 6, lane = t & 63;
  if (lane == 0) pm[wave] = mx;
  __syncthreads();
  mx = fmaxf(fmaxf(pm[0], pm[1]), fmaxf(pm[2], pm[3]));
  float s = 0.f;
#pragma unroll
  for (int k = 0; k < 32; ++k) { v[k] = __expf(v[k] - mx); s += v[k]; }
  s = wave_sum(s);
  if (lane == 0) ps[wave] = s;
  __syncthreads();
  s = (ps[0] + ps[1]) + (ps[2] + ps[3]);
  float inv = 1.f / s;
#pragma unroll
  for (int k = 0; k < 32; ++k) po[(size_t)(t + 256 * k) * C_] = v[k] * inv;
}

extern "C" void kernel_launch(void* const* d_in, const int* in_sizes, int n_in,
                              void* d_out, int out_size, void* d_ws, size_t ws_size,
                              hipStream_t stream) {
  const float* x   = (const float*)d_in[0];
  const float* adj = (const float*)d_in[1];
  const float* W1  = (const float*)d_in[2];
  const float* b1  = (const float*)d_in[3];
  const float* W2  = (const float*)d_in[4];
  const float* b2  = (const float*)d_in[5];
  const float* Wp  = (const float*)d_in[6];
  const float* bp  = (const float*)d_in[7];
  float* out = (float*)d_out;
  char* ws = (char*)d_ws;

  // layout: peak 172.1 MB
  size_t o = 0;
  u16*   adjT = (u16*)(ws + o);   o += (size_t)N_ * N_ * 2;        // 128 MB
  float* rsum = (float*)(ws + o); o += (size_t)N_ * 4;             // 32 KB
  float* rr   = (float*)(ws + o); o += (size_t)N_ * 4;             // 32 KB
  float* g1n  = (float*)(ws + o); o += (size_t)N_ * 512 * 4;       // 16 MB
  u16*   g1t  = (u16*)(ws + o);   o += (size_t)512 * N_ * 2;       // 8 MB
  u16*   xt   = (u16*)(ws + o);   o += (size_t)256 * N_ * 2;       // 4 MB
  u16*   Tp   = (u16*)(ws + o);   o += (size_t)4 * 256 * N_ * 2;   // 16 MB (T1p KS=4 / T2p KS=2)
  u16*   T1p  = Tp;
  u16*   T2p  = Tp;
  // adjT region dead after GEMM2:
  float* g2n  = (float*)ws;                                         // 32 MB
  float* pred = (float*)(ws + (size_t)33554432);                    // 2 MB

  k_zero     <<<N_ / 256, 256, 0, stream>>>(rsum, N_);
  k_transpose<<<128 * 128, 256, 0, stream>>>(adj, adjT, rsum);
  k_rsqrt    <<<N_ / 256, 256, 0, stream>>>(rsum, rr);
  k_xt       <<<4 * 128, 256, 0, stream>>>(x, rr, xt);
  k_gemmT<4> <<<(256 / 64) * 4 * (N_ / 256), 256, 0, stream>>>(xt, adjT, T1p, 256);   // 512 blocks
  k_epi1     <<<N_ / 16, 256, 0, stream>>>(T1p, x, rr, W1, b1, g1n, g1t);
  k_gemmT<2> <<<(512 / 64) * 2 * (N_ / 256), 256, 0, stream>>>(g1t, adjT, T2p, 512);  // 512 blocks
  k_epi2     <<<N_ / 8, 256, 0, stream>>>(T2p, g1n, rr, W2, b2, g2n);
  k_pred     <<<N_ / 8, 256, 0, stream>>>(g2n, Wp, bp, pred);
  k_softmax  <<<64, 256, 0, stream>>>(pred, out);
}

// Round 4
// 731.980 us; speedup vs baseline: 1.3779x; 1.3779x over previous
//
#include <hip/hip_runtime.h>
#include <hip/hip_bf16.h>
#include <cstdint>
#include <cstddef>

typedef unsigned short u16;
typedef __attribute__((ext_vector_type(8))) short bf16x8;   // MFMA A/B frag (8 bf16)
typedef __attribute__((ext_vector_type(4))) float f32x4;    // MFMA C/D frag
typedef __attribute__((ext_vector_type(4))) unsigned short u16x4;

#define B_ 4
#define N_ 8192
#define D_ 64
#define H_ 128
#define E_ 256
#define C_ 16

// ---------- helpers ----------
__device__ __forceinline__ u16 f2bf(float f) {
  unsigned u = __builtin_bit_cast(unsigned, f);
  u += 0x7fffu + ((u >> 16) & 1u);          // RNE
  return (u16)(u >> 16);
}
__device__ __forceinline__ float bf2f(u16 u) {
  return __builtin_bit_cast(float, ((unsigned)u) << 16);
}

__device__ __forceinline__ float wave_sum(float v) {
  v += __shfl_xor(v, 32, 64); v += __shfl_xor(v, 16, 64); v += __shfl_xor(v, 8, 64);
  v += __shfl_xor(v, 4, 64);  v += __shfl_xor(v, 2, 64);  v += __shfl_xor(v, 1, 64);
  return v;
}
__device__ __forceinline__ float wave_max(float v) {
  v = fmaxf(v, __shfl_xor(v, 32, 64)); v = fmaxf(v, __shfl_xor(v, 16, 64));
  v = fmaxf(v, __shfl_xor(v, 8, 64));  v = fmaxf(v, __shfl_xor(v, 4, 64));
  v = fmaxf(v, __shfl_xor(v, 2, 64));  v = fmaxf(v, __shfl_xor(v, 1, 64));
  return v;
}

__device__ __forceinline__ void gld16(const void* g, void* l) {
  __builtin_amdgcn_global_load_lds((const __attribute__((address_space(1))) void*)g,
                                   (__attribute__((address_space(3))) void*)l, 16, 0, 0);
}

// ---------- zero init (for atomic rowsum) ----------
__global__ __launch_bounds__(256) void k_zero(float* __restrict__ p, int n) {
  int i = blockIdx.x * 256 + threadIdx.x;
  if (i < n) p[i] = 0.f;
}

// ---------- transpose + fused rowsum: adjT[i][j]=bf16(adj[j][i]); rsum[j]+=partial ----------
__global__ __launch_bounds__(256) void k_transpose(const float* __restrict__ adj, u16* __restrict__ adjT,
                                                   float* __restrict__ rsum) {
  __shared__ float tile[64][65];
  int bi = blockIdx.x & 127, bj = blockIdx.x >> 7;
  int i0 = bi * 64, j0 = bj * 64;
  int t = threadIdx.x;
#pragma unroll
  for (int q = 0; q < 4; ++q) {
    int idx = q * 256 + t; int jl = idx >> 4, c4 = idx & 15;
    float4 v = *(const float4*)(adj + (size_t)(j0 + jl) * N_ + i0 + c4 * 4);
    tile[jl][c4 * 4 + 0] = v.x; tile[jl][c4 * 4 + 1] = v.y;
    tile[jl][c4 * 4 + 2] = v.z; tile[jl][c4 * 4 + 3] = v.w;
    float s = (v.x + v.y) + (v.z + v.w);
    s += __shfl_xor(s, 1, 64); s += __shfl_xor(s, 2, 64);
    s += __shfl_xor(s, 4, 64); s += __shfl_xor(s, 8, 64);
    if ((t & 15) == 0) atomicAdd(&rsum[j0 + jl], s);
  }
  __syncthreads();
#pragma unroll
  for (int q = 0; q < 4; ++q) {
    int idx = q * 256 + t; int il = idx >> 4, c4 = idx & 15;
    u16x4 o;
    o.x = f2bf(tile[c4 * 4 + 0][il]); o.y = f2bf(tile[c4 * 4 + 1][il]);
    o.z = f2bf(tile[c4 * 4 + 2][il]); o.w = f2bf(tile[c4 * 4 + 3][il]);
    *(u16x4*)(adjT + (size_t)(i0 + il) * N_ + j0 + c4 * 4) = o;
  }
}

// ---------- rsum -> rr = rsum^-0.5 ----------
__global__ __launch_bounds__(256) void k_rsqrt(const float* __restrict__ rsum, float* __restrict__ rr) {
  int i = blockIdx.x * 256 + threadIdx.x;
  float s = rsum[i];
  rr[i] = s > 0.f ? rsqrtf(s) : 0.f;
}

// ---------- xt[b*64+d][j] = bf16(x[b][j][d] * r[j]) ----------
__global__ __launch_bounds__(256) void k_xt(const float* __restrict__ x, const float* __restrict__ rr,
                                            u16* __restrict__ xt) {
  __shared__ float tile[64][65];
  int b = blockIdx.x >> 7, j0 = (blockIdx.x & 127) * 64;
  int t = threadIdx.x;
#pragma unroll
  for (int q = 0; q < 4; ++q) {
    int idx = q * 256 + t; int jl = idx >> 4, c4 = idx & 15;
    float4 v = *(const float4*)(x + ((size_t)b * N_ + j0 + jl) * D_ + c4 * 4);
    float rv = rr[j0 + jl];
    tile[jl][c4 * 4 + 0] = v.x * rv; tile[jl][c4 * 4 + 1] = v.y * rv;
    tile[jl][c4 * 4 + 2] = v.z * rv; tile[jl][c4 * 4 + 3] = v.w * rv;
  }
  __syncthreads();
#pragma unroll
  for (int q = 0; q < 4; ++q) {
    int idx = q * 256 + t; int dl = idx >> 4, c4 = idx & 15;
    u16x4 o;
    o.x = f2bf(tile[c4 * 4 + 0][dl]); o.y = f2bf(tile[c4 * 4 + 1][dl]);
    o.z = f2bf(tile[c4 * 4 + 2][dl]); o.w = f2bf(tile[c4 * 4 + 3][dl]);
    *(u16x4*)(xt + (size_t)(b * 64 + dl) * N_ + j0 + c4 * 4) = o;
  }
}

// ---------- GEMM: Cp[ks][i][c] = bf16( sum_{k in slice} adjT[i][k] * Bt[c][k] ) ----------
// A = adjT (8192 rows, read ~once thanks to XCD grouping), B = xt/g1t (small, L2-resident).
// BM=BN=128, BK=32, 4 waves (m97 shape). NB = channel blocks; the NB blocks sharing an
// A-tile get blockIdx differing by multiples of 8 -> same XCD, temporally adjacent.
// kb is slowest so co-resident blocks share the same small B slice.
template<int NBLOG, int KS>
__global__ __launch_bounds__(256) void k_gemmA(const u16* __restrict__ A, const u16* __restrict__ B,
                                               u16* __restrict__ Cp, int NCH) {
  constexpr int NB = 1 << NBLOG;
  constexpr int BK = 32;
  __shared__ __align__(16) u16 As[128 * BK];   // 8 KB
  __shared__ __align__(16) u16 Bs[128 * BK];   // 8 KB
  const int tid = threadIdx.x;
  const int raw = blockIdx.x;
  const int s = raw & (NB * 8 - 1);
  const int bn = s >> 3;
  const int q = (raw >> (NBLOG + 3)) * 8 + (s & 7);
  const int bm = q & 63;           // nmb = 64
  const int kb = q >> 6;           // KS slices
  const int m0 = bm * 128, n0 = bn * 128;
  const int kbeg = kb * (N_ / KS), kend = kbeg + N_ / KS;
  const int wave = tid >> 6, lane = tid & 63;
  const int wm = (wave >> 1) * 64, wn = (wave & 1) * 64;
  const int lr = lane & 15, lk = lane >> 4;

  f32x4 acc[4][4];
#pragma unroll
  for (int a = 0; a < 4; ++a)
#pragma unroll
    for (int b = 0; b < 4; ++b) acc[a][b] = (f32x4){0.f, 0.f, 0.f, 0.f};

  const u16* Ab = A + (size_t)m0 * N_;
  const u16* Bb = B + (size_t)n0 * N_;

  for (int k0 = kbeg; k0 < kend; k0 += BK) {
#pragma unroll
    for (int it = 0; it < 2; ++it) {
      int c = it * 256 + tid;
      gld16(Ab + (size_t)(c >> 2) * N_ + k0 + (c & 3) * 8,
            As + (it * 256 + (tid & 192)) * 8);
      gld16(Bb + (size_t)(c >> 2) * N_ + k0 + (c & 3) * 8,
            Bs + (it * 256 + (tid & 192)) * 8);
    }
    __syncthreads();
    bf16x8 av[4], bv[4];
#pragma unroll
    for (int f = 0; f < 4; ++f) {
      av[f] = *(const bf16x8*)(As + (wm + f * 16 + lr) * BK + lk * 8);
      bv[f] = *(const bf16x8*)(Bs + (wn + f * 16 + lr) * BK + lk * 8);
    }
#pragma unroll
    for (int fm = 0; fm < 4; ++fm)
#pragma unroll
      for (int fn = 0; fn < 4; ++fn)
        acc[fm][fn] = __builtin_amdgcn_mfma_f32_16x16x32_bf16(av[fm], bv[fn], acc[fm][fn], 0, 0, 0);
    __syncthreads();
  }
  u16* Cs = Cp + (size_t)kb * N_ * NCH;
#pragma unroll
  for (int fm = 0; fm < 4; ++fm) {
    int row0 = m0 + wm + fm * 16 + lk * 4;
#pragma unroll
    for (int fn = 0; fn < 4; ++fn) {
      int col = n0 + wn + fn * 16 + lr;
#pragma unroll
      for (int p = 0; p < 4; ++p)
        Cs[(size_t)(row0 + p) * NCH + col] = f2bf(acc[fm][fn][p]);
    }
  }
}

// ---------- epi1: 16 nodes/block. y=r*sum(T1p)+x ; z=y@W1+b1 ; L2norm ; relu ; BN ; g1n,g1t ----------
// T1p layout: [ks][i][c], KS=4
__global__ __launch_bounds__(256) void k_epi1(const u16* __restrict__ T1p, const float* __restrict__ x,
    const float* __restrict__ rr, const float* __restrict__ W1, const float* __restrict__ b1,
    float* __restrict__ g1n, u16* __restrict__ g1t) {
  union SharedU { float ys[16][256]; u16 gb[512][18]; };
  __shared__ SharedU su;                 // 18 KB
  __shared__ float zbuf[16][512];        // 32 KB
  __shared__ float rs[16];
  const int t = threadIdx.x;
  const int i0 = blockIdx.x * 16;
  constexpr size_t SL = (size_t)N_ * 256;
  if (t < 16) rs[t] = rr[i0 + t];
  __syncthreads();
  // phase 0: ys[n][c] = r*sum_ks T1p + x   (c = b*64+d)
#pragma unroll
  for (int q = 0; q < 16; ++q) {
    int idx = q * 256 + t; int n = idx >> 8, c = idx & 255, b = c >> 6, d = c & 63;
    size_t ti = (size_t)(i0 + n) * 256 + c;
    float s = bf2f(T1p[ti]) + bf2f(T1p[ti + SL]) + bf2f(T1p[ti + 2 * SL]) + bf2f(T1p[ti + 3 * SL]);
    su.ys[n][c] = rs[n] * s + x[((size_t)b * N_ + i0 + n) * D_ + d];
  }
  // phase 1: W1 column into registers
  const int h = t & 127, bh = t >> 7;
  float w[64];
#pragma unroll
  for (int d = 0; d < 64; ++d) w[d] = W1[d * H_ + h];
  float b1h = b1[h];
  __syncthreads();
  // phase 2: z[n][c'] for c' = b*128+h
  for (int n = 0; n < 16; ++n) {
    float za = b1h, zb = b1h;
#pragma unroll
    for (int d = 0; d < 64; ++d) {
      za += su.ys[n][bh * 64 + d] * w[d];
      zb += su.ys[n][(bh + 2) * 64 + d] * w[d];
    }
    zbuf[n][bh * 128 + h] = za;
    zbuf[n][(bh + 2) * 128 + h] = zb;
  }
  __syncthreads();
  // phase 3: per-wave nodes, no barriers
  const int wv = t >> 6, lane = t & 63;
#pragma unroll
  for (int nn = 0; nn < 4; ++nn) {
    int n = wv * 4 + nn;
    float v[8], nb2[8];
#pragma unroll
    for (int q = 0; q < 8; ++q) { v[q] = zbuf[n][q * 64 + lane]; }
#pragma unroll
    for (int q = 0; q < 8; ++q) nb2[q] = wave_sum(v[q] * v[q]);
    float inv0 = 1.f / fmaxf(sqrtf(nb2[0] + nb2[1]), 1e-12f);
    float inv1 = 1.f / fmaxf(sqrtf(nb2[2] + nb2[3]), 1e-12f);
    float inv2 = 1.f / fmaxf(sqrtf(nb2[4] + nb2[5]), 1e-12f);
    float inv3 = 1.f / fmaxf(sqrtf(nb2[6] + nb2[7]), 1e-12f);
    float sc[4] = {inv0, inv1, inv2, inv3};
    float t1 = 0.f, t2 = 0.f;
#pragma unroll
    for (int q = 0; q < 8; ++q) {
      v[q] = fmaxf(v[q] * sc[q >> 1], 0.f);
      t1 += v[q]; t2 += v[q] * v[q];
    }
    float s1 = wave_sum(t1), s2 = wave_sum(t2);
    float m = s1 * (1.f / 512.f);
    float var = s2 * (1.f / 512.f) - m * m;
    float iv = rsqrtf(var + 1e-5f);
    float rv = rs[n];
#pragma unroll
    for (int q = 0; q < 8; ++q) {
      float g = (v[q] - m) * iv;
      g1n[(size_t)(i0 + n) * 512 + q * 64 + lane] = g;
      su.gb[q * 64 + lane][n] = f2bf(g * rv);
    }
  }
  __syncthreads();
  // phase 4: coalesced transposed write of g1t [c][j]
#pragma unroll
  for (int rep = 0; rep < 2; ++rep) {
    int c = rep * 256 + t;
    const unsigned* src = (const unsigned*)&su.gb[c][0];
    uint4 o0, o1;
    o0.x = src[0]; o0.y = src[1]; o0.z = src[2]; o0.w = src[3];
    o1.x = src[4]; o1.y = src[5]; o1.z = src[6]; o1.w = src[7];
    uint4* dst = (uint4*)(g1t + (size_t)c * N_ + i0);
    dst[0] = o0; dst[1] = o1;
  }
}

// ---------- epi2: y=r*sum(T2p)+g1 ; z=y@W2+b2 ; L2norm(e) ; relu ; BN ; g2n ----------
// T2p layout: [ks][i][c], KS=2
__global__ __launch_bounds__(256) void k_epi2(const u16* __restrict__ T2p, const float* __restrict__ g1n,
    const float* __restrict__ rr, const float* __restrict__ W2, const float* __restrict__ b2,
    float* __restrict__ g2n) {
  __shared__ __align__(16) float ysm[8 * 512];     // 16 KB
  __shared__ __align__(16) float W2s[32 * 256];    // 32 KB
  __shared__ float red1[128];
  __shared__ float nv[32];
  __shared__ float redA[32], redB[32];
  __shared__ float mn[8], iv[8];
  constexpr size_t SL = (size_t)N_ * 512;
  int i0 = blockIdx.x * 8, t = threadIdx.x;
#pragma unroll
  for (int q = 0; q < 4; ++q) {
    int idx = q * 256 + t; int n = idx >> 7, c4 = idx & 127;
    int i = i0 + n;
    float rv = rr[i];
    size_t ti = (size_t)i * 512 + c4 * 4;
    u16x4 p0 = *(const u16x4*)(T2p + ti);
    u16x4 p1 = *(const u16x4*)(T2p + SL + ti);
    float4 g = *(const float4*)(g1n + ti);
    float4 y;
    y.x = rv * (bf2f(p0.x) + bf2f(p1.x)) + g.x;
    y.y = rv * (bf2f(p0.y) + bf2f(p1.y)) + g.y;
    y.z = rv * (bf2f(p0.z) + bf2f(p1.z)) + g.z;
    y.w = rv * (bf2f(p0.w) + bf2f(p1.w)) + g.w;
    *(float4*)&ysm[n * 512 + c4 * 4] = y;
  }
  int e = t;
  float z[8][4];
#pragma unroll
  for (int n = 0; n < 8; ++n)
#pragma unroll
    for (int b = 0; b < 4; ++b) z[n][b] = 0.f;

  for (int hc = 0; hc < H_; hc += 32) {
    __syncthreads();
#pragma unroll
    for (int q = 0; q < 8; ++q) {
      int idx = q * 256 + t;
      ((float4*)W2s)[idx] = ((const float4*)(W2 + (size_t)hc * 256))[idx];
    }
    __syncthreads();
#pragma unroll
    for (int h4 = 0; h4 < 32; h4 += 4) {
      float w0 = W2s[(h4 + 0) * 256 + e];
      float w1 = W2s[(h4 + 1) * 256 + e];
      float w2 = W2s[(h4 + 2) * 256 + e];
      float w3 = W2s[(h4 + 3) * 256 + e];
#pragma unroll
      for (int n = 0; n < 8; ++n) {
#pragma unroll
        for (int b = 0; b < 4; ++b) {
          float4 y = *(const float4*)&ysm[n * 512 + b * 128 + hc + h4];
          z[n][b] += y.x * w0 + y.y * w1 + y.z * w2 + y.w * w3;
        }
      }
    }
  }
  float b2e = b2[e];
  int wave = t >> 6, lane = t & 63;
#pragma unroll
  for (int n = 0; n < 8; ++n)
#pragma unroll
    for (int b = 0; b < 4; ++b) {
      z[n][b] += b2e;
      float s = wave_sum(z[n][b] * z[n][b]);
      if (lane == 0) red1[n * 16 + b * 4 + wave] = s;
    }
  __syncthreads();
  if (t < 32) {
    float s = red1[t * 4 + 0] + red1[t * 4 + 1] + red1[t * 4 + 2] + red1[t * 4 + 3];
    nv[t] = fmaxf(sqrtf(s), 1e-12f);
  }
  __syncthreads();
#pragma unroll
  for (int n = 0; n < 8; ++n) {
    float s1 = 0.f, s2 = 0.f;
#pragma unroll
    for (int b = 0; b < 4; ++b) {
      z[n][b] = fmaxf(z[n][b] / nv[n * 4 + b], 0.f);
      s1 += z[n][b]; s2 += z[n][b] * z[n][b];
    }
    s1 = wave_sum(s1); s2 = wave_sum(s2);
    if (lane == 0) { redA[n * 4 + wave] = s1; redB[n * 4 + wave] = s2; }
  }
  __syncthreads();
  if (t < 8) {
    float s1 = redA[t * 4] + redA[t * 4 + 1] + redA[t * 4 + 2] + redA[t * 4 + 3];
    float s2 = redB[t * 4] + redB[t * 4 + 1] + redB[t * 4 + 2] + redB[t * 4 + 3];
    float m = s1 * (1.f / 1024.f), v = s2 * (1.f / 1024.f) - m * m;
    mn[t] = m; iv[t] = 1.f / sqrtf(v + 1e-5f);
  }
  __syncthreads();
#pragma unroll
  for (int n = 0; n < 8; ++n)
#pragma unroll
    for (int b = 0; b < 4; ++b)
      g2n[(size_t)(i0 + n) * 1024 + b * 256 + e] = (z[n][b] - mn[n]) * iv[n];
}

// ---------- pred ----------
__global__ __launch_bounds__(256) void k_pred(const float* __restrict__ g2n, const float* __restrict__ Wp,
    const float* __restrict__ bp, float* __restrict__ pred) {
  __shared__ __align__(16) float gs[8 * 1028];
  __shared__ __align__(16) float Wps[E_ * C_];
  int i0 = blockIdx.x * 8, t = threadIdx.x;
#pragma unroll
  for (int q = 0; q < 4; ++q) ((float4*)Wps)[q * 256 + t] = ((const float4*)Wp)[q * 256 + t];
#pragma unroll
  for (int q = 0; q < 8; ++q) {
    int idx = q * 256 + t; int n = idx >> 8, c4 = idx & 255;
    *(float4*)&gs[n * 1028 + c4 * 4] = *(const float4*)(g2n + (size_t)(i0 + n) * 1024 + c4 * 4);
  }
  __syncthreads();
#pragma unroll
  for (int s = 0; s < 2; ++s) {
    int o = s * 256 + t; int n = o >> 6, b = (o >> 4) & 3, c = o & 15;
    float acc = bp[c];
    const float* g = &gs[n * 1028 + b * 256];
#pragma unroll 16
    for (int e2 = 0; e2 < 256; e2 += 4) {
      float4 gv = *(const float4*)&g[e2];
      acc += gv.x * Wps[(e2 + 0) * 16 + c] + gv.y * Wps[(e2 + 1) * 16 + c]
           + gv.z * Wps[(e2 + 2) * 16 + c] + gv.w * Wps[(e2 + 3) * 16 + c];
    }
    pred[((size_t)b * N_ + i0 + n) * C_ + c] = acc;
  }
}

// ---------- softmax over node axis ----------
__global__ __launch_bounds__(256) void k_softmax(const float* __restrict__ pred, float* __restrict__ out) {
  int b = blockIdx.x >> 4, c = blockIdx.x & 15, t = threadIdx.x;
  const float* p = pred + (size_t)b * N_ * C_ + c;
  float* po = out + (size_t)b * N_ * C_ + c;
  float v[32];
  float mx = -3.4e38f;
#pragma unroll
  for (int k = 0; k < 32; ++k) { v[k] = p[(size_t)(t + 256 * k) * C_]; mx = fmaxf(mx, v[k]); }
  mx = wave_max(mx);
  __shared__ float pm[4];
  __shared__ float ps[4];
  int wave = t >> 6, lane = t & 63;
  if (lane == 0) pm[wave] = mx;
  __syncthreads();
  mx = fmaxf(fmaxf(pm[0], pm[1]), fmaxf(pm[2], pm[3]));
  float s = 0.f;
#pragma unroll
  for (int k = 0; k < 32; ++k) { v[k] = __expf(v[k] - mx); s += v[k]; }
  s = wave_sum(s);
  if (lane == 0) ps[wave] = s;
  __syncthreads();
  s = (ps[0] + ps[1]) + (ps[2] + ps[3]);
  float inv = 1.f / s;
#pragma unroll
  for (int k = 0; k < 32; ++k) po[(size_t)(t + 256 * k) * C_] = v[k] * inv;
}

extern "C" void kernel_launch(void* const* d_in, const int* in_sizes, int n_in,
                              void* d_out, int out_size, void* d_ws, size_t ws_size,
                              hipStream_t stream) {
  const float* x   = (const float*)d_in[0];
  const float* adj = (const float*)d_in[1];
  const float* W1  = (const float*)d_in[2];
  const float* b1  = (const float*)d_in[3];
  const float* W2  = (const float*)d_in[4];
  const float* b2  = (const float*)d_in[5];
  const float* Wp  = (const float*)d_in[6];
  const float* bp  = (const float*)d_in[7];
  float* out = (float*)d_out;
  char* ws = (char*)d_ws;

  // layout: peak 172.1 MB (proven in round 3)
  size_t o = 0;
  u16*   adjT = (u16*)(ws + o);   o += (size_t)N_ * N_ * 2;        // 128 MB
  float* rsum = (float*)(ws + o); o += (size_t)N_ * 4;             // 32 KB
  float* rr   = (float*)(ws + o); o += (size_t)N_ * 4;             // 32 KB
  float* g1n  = (float*)(ws + o); o += (size_t)N_ * 512 * 4;       // 16 MB
  u16*   g1t  = (u16*)(ws + o);   o += (size_t)512 * N_ * 2;       // 8 MB
  u16*   xt   = (u16*)(ws + o);   o += (size_t)256 * N_ * 2;       // 4 MB
  u16*   Tp   = (u16*)(ws + o);   o += (size_t)4 * 256 * N_ * 2;   // 16 MB (T1p KS=4 / T2p KS=2)
  u16*   T1p  = Tp;
  u16*   T2p  = Tp;
  // adjT region dead after GEMM2:
  float* g2n  = (float*)ws;                                         // 32 MB
  float* pred = (float*)(ws + (size_t)33554432);                    // 2 MB

  k_zero       <<<N_ / 256, 256, 0, stream>>>(rsum, N_);
  k_transpose  <<<128 * 128, 256, 0, stream>>>(adj, adjT, rsum);
  k_rsqrt      <<<N_ / 256, 256, 0, stream>>>(rsum, rr);
  k_xt         <<<4 * 128, 256, 0, stream>>>(x, rr, xt);
  // GEMM1: NB=2 (256 ch / 128), KS=4 -> 2*64*4 = 512 blocks
  k_gemmA<1, 4><<<512, 256, 0, stream>>>(adjT, xt, T1p, 256);
  k_epi1       <<<N_ / 16, 256, 0, stream>>>(T1p, x, rr, W1, b1, g1n, g1t);
  // GEMM2: NB=4 (512 ch / 128), KS=2 -> 4*64*2 = 512 blocks
  k_gemmA<2, 2><<<512, 256, 0, stream>>>(adjT, g1t, T2p, 512);
  k_epi2       <<<N_ / 8, 256, 0, stream>>>(T2p, g1n, rr, W2, b2, g2n);
  k_pred       <<<N_ / 8, 256, 0, stream>>>(g2n, Wp, bp, pred);
  k_softmax    <<<64, 256, 0, stream>>>(pred, out);
}